// Round 1
// 829.665 us; speedup vs baseline: 1.0033x; 1.0033x over previous
//
#include <hip/hip_runtime.h>
#include <stdint.h>

// CMValidator: per batch (B=262144) of 5 vertices in R^128:
//   - 10 pairwise squared distances (output 0, B x 10)
//   - squared simplex volume via Cayley-Menger det (output 1, B x 1)
// Memory-bound: 671 MB read, 11.5 MB write -> ~108 us floor at 6.3 TB/s.
//
// Round-3 change vs round-2: global loads were 4x256B discontiguous segments
// per wave instruction (16 lanes/batch, batch stride 2560 B). Now each wave
// stages its own 4 batches (10 KB) into LDS via global_load_lds width=16 --
// every VMEM instruction is a single contiguous 1 KB segment -- then reads
// the 16-lane-per-batch compute layout back via ds_read_b128. The staged LDS
// region is wave-private: no __syncthreads, just s_waitcnt vmcnt(0).
// Compute/reduction/det path is byte-identical to round-2 (verified passing).
//
// 6x6 CM det reduced analytically: det(CM) = -det(S), S 4x4 symmetric with
//   S[ii] = -2*d2[0][i+1],  S[ij] = d2[i+1][j+1] - d2[0][i+1] - d2[0][j+1]
// vol2 = PREFACTOR * det(CM) = det(S)/9216.

template <int CTRL>
__device__ __forceinline__ float row_rotadd(float x) {
    int r = __builtin_amdgcn_update_dpp(0, __builtin_bit_cast(int, x),
                                        CTRL, 0xF, 0xF, false);
    return x + __builtin_bit_cast(float, r);
}

// Full 16-lane (DPP row) sum; every lane of the row ends with the total.
__device__ __forceinline__ float row_reduce16(float x) {
    x = row_rotadd<0x121>(x);  // row_ror:1
    x = row_rotadd<0x122>(x);  // row_ror:2
    x = row_rotadd<0x124>(x);  // row_ror:4
    x = row_rotadd<0x128>(x);  // row_ror:8
    return x;
}

__device__ __forceinline__ void compute_and_store(const float4 (&v)[5][2],
                                                  int b, int sl,
                                                  float* __restrict__ out,
                                                  int B) {
    // 10 pairwise squared-distance partials, combinations(5,2) order:
    // (0,1)(0,2)(0,3)(0,4)(1,2)(1,3)(1,4)(2,3)(2,4)(3,4)
    float acc[10];
    {
        int idx = 0;
#pragma unroll
        for (int i = 0; i < 5; ++i) {
#pragma unroll
            for (int j = i + 1; j < 5; ++j) {
                float d, s;
                d = v[i][0].x - v[j][0].x; s = d * d;
                d = v[i][0].y - v[j][0].y; s = fmaf(d, d, s);
                d = v[i][0].z - v[j][0].z; s = fmaf(d, d, s);
                d = v[i][0].w - v[j][0].w; s = fmaf(d, d, s);
                d = v[i][1].x - v[j][1].x; s = fmaf(d, d, s);
                d = v[i][1].y - v[j][1].y; s = fmaf(d, d, s);
                d = v[i][1].z - v[j][1].z; s = fmaf(d, d, s);
                d = v[i][1].w - v[j][1].w; s = fmaf(d, d, s);
                acc[idx++] = s;
            }
        }
    }

    // Pure-VALU 16-lane reduction (no LDS pipe, no lgkmcnt stalls).
    float p0 = row_reduce16(acc[0]);
    float p1 = row_reduce16(acc[1]);
    float p2 = row_reduce16(acc[2]);
    float p3 = row_reduce16(acc[3]);
    float p4 = row_reduce16(acc[4]);
    float p5 = row_reduce16(acc[5]);
    float p6 = row_reduce16(acc[6]);
    float p7 = row_reduce16(acc[7]);
    float p8 = row_reduce16(acc[8]);
    float p9 = row_reduce16(acc[9]);

    // 4x4 reduced CM matrix S (symmetric)
    const float m00 = -2.0f * p0;
    const float m11 = -2.0f * p1;
    const float m22 = -2.0f * p2;
    const float m33 = -2.0f * p3;
    const float m01 = p4 - p0 - p1;
    const float m02 = p5 - p0 - p2;
    const float m03 = p6 - p0 - p3;
    const float m12 = p7 - p1 - p2;
    const float m13 = p8 - p1 - p3;
    const float m23 = p9 - p2 - p3;

    // det(S) via 2x2-minor expansion (symmetric: m10=m01, etc.)
    const float A  = m00 * m11 - m01 * m01;
    const float Bb = m00 * m12 - m02 * m01;
    const float C  = m00 * m13 - m03 * m01;
    const float D  = m01 * m12 - m02 * m11;
    const float E  = m01 * m13 - m03 * m11;
    const float F  = m02 * m13 - m03 * m12;
    const float G  = m02 * m13 - m12 * m03;  // rows 2,3 cols 0,1
    const float H  = m02 * m23 - m22 * m03;
    const float I  = m02 * m33 - m23 * m03;
    const float J  = m12 * m23 - m22 * m13;
    const float Kk = m12 * m33 - m23 * m13;
    const float L  = m22 * m33 - m23 * m23;

    const float detS = A * L - Bb * Kk + C * J + D * I - E * H + F * G;
    const float vol2 = detS * (1.0f / 9216.0f);

    // Output 0: d2_pairs, lanes 0..9 of each 16-lane group.
    float pv = p0;
    pv = (sl == 1) ? p1 : pv;
    pv = (sl == 2) ? p2 : pv;
    pv = (sl == 3) ? p3 : pv;
    pv = (sl == 4) ? p4 : pv;
    pv = (sl == 5) ? p5 : pv;
    pv = (sl == 6) ? p6 : pv;
    pv = (sl == 7) ? p7 : pv;
    pv = (sl == 8) ? p8 : pv;
    pv = (sl == 9) ? p9 : pv;
    if (sl < 10)
        out[(size_t)b * 10 + sl] = fmaxf(pv, 0.0f);

    // Output 1: vol2 at offset B*10
    if (sl == 10)
        out[(size_t)B * 10 + b] = vol2;
}

__global__ __launch_bounds__(256) void cm_kernel(const float* __restrict__ verts,
                                                 float* __restrict__ out,
                                                 int B) {
    // 16 batches per block = 16 * 640 floats = 40 KB staged in LDS.
    __shared__ float smem[16 * 640];

    const int tid  = threadIdx.x;
    const int wid  = tid >> 6;    // wave 0..3
    const int lane = tid & 63;
    const int sl   = lane & 15;   // sub-lane within 16-lane batch group
    const int b0   = blockIdx.x * 16;

    if (b0 + 16 <= B) {
        // ---- fast path: wave-contiguous global -> LDS staging ----
        // Wave wid owns batches [b0+4*wid, b0+4*wid+4) = 10 KB contiguous.
        // Each of the 10 global_load_lds covers ONE contiguous 1 KB segment:
        // per-lane global addr = base + k*1024 + lane*16; LDS dest is the
        // wave-uniform base + lane*16 (linear, matches global order).
        const float* gsrc = verts + (size_t)(b0 + wid * 4) * 640 + lane * 4;
        float* lbase = &smem[wid * 2560];
#pragma unroll
        for (int k = 0; k < 10; ++k) {
            __builtin_amdgcn_global_load_lds(
                (const __attribute__((address_space(1))) float*)(gsrc + k * 256),
                (__attribute__((address_space(3))) float*)(lbase + k * 256),
                16, 0, 0);
        }
        // Wave-private region: no barrier needed, only drain our own loads.
        asm volatile("s_waitcnt vmcnt(0)" ::: "memory");

        // LDS -> regs in the 16-lane-per-batch compute layout.
        // Each 16-lane phase of a ds_read_b128 reads 256 B contiguous
        // (all 32 banks x 2) -> conflict-free.
        const float4* lsrc =
            (const float4*)&smem[wid * 2560 + (lane >> 4) * 640];
        float4 v[5][2];
#pragma unroll
        for (int i = 0; i < 5; ++i) {
            v[i][0] = lsrc[i * 32 + sl];        // dims [4sl, 4sl+4)
            v[i][1] = lsrc[i * 32 + 16 + sl];   // dims [64+4sl, 64+4sl+4)
        }
        const int b = b0 + wid * 4 + (lane >> 4);
        compute_and_store(v, b, sl, out, B);
    } else {
        // ---- tail path (B not a multiple of 16): original direct loads ----
        const int b = b0 + wid * 4 + (lane >> 4);
        if (b >= B) return;
        const float4* base = (const float4*)(verts + (size_t)b * 640);
        float4 v[5][2];
#pragma unroll
        for (int i = 0; i < 5; ++i) {
            v[i][0] = base[i * 32 + sl];
            v[i][1] = base[i * 32 + 16 + sl];
        }
        compute_and_store(v, b, sl, out, B);
    }
}

extern "C" void kernel_launch(void* const* d_in, const int* in_sizes, int n_in,
                              void* d_out, int out_size, void* d_ws, size_t ws_size,
                              hipStream_t stream) {
    const float* verts = (const float*)d_in[0];
    float* out = (float*)d_out;
    const int B = in_sizes[0] / (5 * 128);

    const int threads = 256;                        // 4 waves, 16 batches/block
    const int blocks = (B * 16 + threads - 1) / threads;
    hipLaunchKernelGGL(cm_kernel, dim3(blocks), dim3(threads), 0, stream,
                       verts, out, B);
}